// Round 12
// baseline (214.778 us; speedup 1.0000x reference)
//
#include <hip/hip_runtime.h>
#include <hip/hip_bf16.h>

// B=4 H=16 S=2048 D=64, f32 in/out.
// Round 12: r9 quarter-structure with KVB=128 (NT=16): half the barriers,
// half the loop overhead. Two-phase staging (issueA/stageA/issueB/stageB)
// keeps register peak identical to r9 (~64 arch + 48 acc).

constexpr int Bb = 4, Hh = 16, Ss = 2048, Dd = 64;
constexpr float SCALE_LOG2E = 0.125f * 1.4426950408889634f; // D^-0.5 * log2(e)
constexpr int KVB = 128;
constexpr int NT = Ss / KVB;

typedef __bf16 bf16x8 __attribute__((ext_vector_type(8)));
typedef float  f32x4  __attribute__((ext_vector_type(4)));
typedef float  f32x16 __attribute__((ext_vector_type(16)));
typedef unsigned int u32x4 __attribute__((ext_vector_type(4)));

__device__ __forceinline__ unsigned cvtpk(float lo, float hi) {
  unsigned r;
  asm("v_cvt_pk_bf16_f32 %0, %1, %2" : "=v"(r) : "v"(lo), "v"(hi));
  return r;  // lo -> D[15:0], hi -> D[31:16]
}
// a.r1 <-> b.r0 (rows = 32-lane halves). After: a=[a.r0,b.r0], b=[a.r1,b.r1].
__device__ __forceinline__ void permswap(unsigned &a, unsigned &b) {
  asm("v_permlane32_swap_b32 %0, %1" : "+v"(a), "+v"(b));
}

__global__ __launch_bounds__(512, 4)
void sdpa_fwd(const float* __restrict__ Qg, const float* __restrict__ Kg,
              const float* __restrict__ Vg, float* __restrict__ Og) {
  // K[2]: 2x16KB at 0, VT[2]: 2x16KB at 32768. K rows 128B (^ (row&7)<<4);
  // VT rows 256B (kv axis, ^ (d&7)<<4). Epilogue overlays first 33792B.
  __shared__ __align__(16) char smem[65536];

  const int tid = threadIdx.x;
  const int wave = tid >> 6, lane = tid & 63;
  const int lq = lane & 31, hi = lane >> 5;
  const int swz = (lq & 7) << 4;

  const int bh = blockIdx.x * 8 + (blockIdx.y >> 3);
  const int qt = blockIdx.y & 7;
  const size_t base = (size_t)bh * (Ss * Dd);
  const int qw = qt * 256 + wave * 32;        // wave owns q rows [qw, qw+32)

  const float* Qp = Qg + base;
  const float* Kp = Kg + base;
  const float* Vp = Vg + base;

  // staging role split: waves 0-3 stage K, waves 4-7 stage V; each half-tile
  // (64 kv rows) is staged by 256 threads exactly as in r9.
  const bool isK = (wave < 4);
  const int st  = tid & 255;
  const int skv = st >> 2, s4 = st & 3;       // K: row skv(+64h), 16 cols @16*s4
  const int r2  = st >> 3, s8 = st & 7;       // V: rows 2r2,2r2+1(+64h), d=s8+8j

  // loop-invariant LDS read offsets (col-select ^ swizzle), bits 4-6
  int roff[4];
#pragma unroll
  for (int ds = 0; ds < 4; ++ds) roff[ds] = (32 * ds + 16 * hi) ^ swz;

  // ---- Q fragments: B-operand, col=q=lq, k=d=16*ds+8*hi+j ----
  bf16x8 qf[4];
  {
    const float* qp = Qp + (size_t)(qw + lq) * Dd;
#pragma unroll
    for (int ds = 0; ds < 4; ++ds) {
      f32x4 x0 = *(const f32x4*)(qp + 16 * ds + 8 * hi);
      f32x4 x1 = *(const f32x4*)(qp + 16 * ds + 8 * hi + 4);
#pragma unroll
      for (int j = 0; j < 4; ++j) {
        qf[ds][j]     = (__bf16)(x0[j] * SCALE_LOG2E);
        qf[ds][j + 4] = (__bf16)(x1[j] * SCALE_LOG2E);
      }
    }
  }

  f32x16 o[2];   // o[db]: O^T accumulators (d rows 32*db.., q col = lq)
#pragma unroll
  for (int a = 0; a < 2; ++a)
#pragma unroll
    for (int i = 0; i < 16; ++i) o[a][i] = 0.f;
  float ps = 0.f;   // per-lane partial row sum (combine across hi at end)

  f32x4 stg[4];     // staging regs, time-shared between half-tiles

  auto issueH = [&](int t, int half) {
    const int r0 = t * KVB + 64 * half;
    if (isK) {
      const float* kp = Kp + (size_t)(r0 + skv) * Dd + 16 * s4;
#pragma unroll
      for (int i = 0; i < 4; ++i) stg[i] = *(const f32x4*)(kp + 4 * i);
    } else {
      const float* vp = Vp + (size_t)(r0 + 2 * r2) * Dd + s8;
#pragma unroll
      for (int j = 0; j < 8; ++j) {
        stg[j >> 2][j & 3]       = vp[8 * j];        // row r0+2r2
        stg[2 + (j >> 2)][j & 3] = vp[Dd + 8 * j];   // row r0+2r2+1
      }
    }
  };
  auto stageH = [&](int buf, int half) {
    char* kb = smem + buf * 16384;
    char* vb = smem + 32768 + buf * 16384;
    if (isK) {
      const int row = 64 * half + skv;
#pragma unroll
      for (int c = 0; c < 2; ++c) {          // 2 x b128, swizzled slot
        u32x4 u;
        u[0] = cvtpk(stg[2 * c][0], stg[2 * c][1]);
        u[1] = cvtpk(stg[2 * c][2], stg[2 * c][3]);
        u[2] = cvtpk(stg[2 * c + 1][0], stg[2 * c + 1][1]);
        u[3] = cvtpk(stg[2 * c + 1][2], stg[2 * c + 1][3]);
        *(u32x4*)(kb + row * 128 + 16 * ((2 * s4 + c) ^ (skv & 7))) = u;
      }
    } else {
      const int colb = 128 * half + 4 * r2;  // kv byte col within 256B row
#pragma unroll
      for (int j = 0; j < 8; ++j) {          // VT: 8 x b32 (kv pair packed)
        int d = s8 + 8 * j;
        *(unsigned*)(vb + d * 256 + (colb ^ ((d & 7) << 4))) =
            cvtpk(stg[j >> 2][j & 3], stg[2 + (j >> 2)][j & 3]);
      }
    }
  };

  // quarter kvq (0..3): QK^T on kv rows 32kvq..32kvq+31 -> SM -> pack -> PV
  auto quarter = [&](const char* kb, const char* vb, int kvq) {
    f32x16 s;
#pragma unroll
    for (int i = 0; i < 16; ++i) s[i] = 0.f;
    __builtin_amdgcn_s_setprio(1);
#pragma unroll
    for (int ds = 0; ds < 4; ++ds) {
      bf16x8 k0 = *(const bf16x8*)(kb + (32 * kvq + lq) * 128 + roff[ds]);
      s = __builtin_amdgcn_mfma_f32_32x32x16_bf16(k0, qf[ds], s, 0, 0, 0);
    }
    __builtin_amdgcn_s_setprio(0);

    // max-free softmax: p = exp2(s); partial row sum
#pragma unroll
    for (int i = 0; i < 16; ++i) s[i] = __builtin_amdgcn_exp2f(s[i]);
    {
      float u0 = 0.f, u1 = 0.f, u2 = 0.f, u3 = 0.f;
#pragma unroll
      for (int i = 0; i < 16; i += 4) {
        u0 += s[i]; u1 += s[i + 1]; u2 += s[i + 2]; u3 += s[i + 3];
      }
      ps += (u0 + u1) + (u2 + u3);
    }
    // pack to B-frags via permlane32_swap (T12)
    bf16x8 pf2[2];
#pragma unroll
    for (int h = 0; h < 2; ++h) {
      const int ofs = 8 * h;
      unsigned x0 = cvtpk(s[ofs + 0], s[ofs + 1]);
      unsigned x1 = cvtpk(s[ofs + 2], s[ofs + 3]);
      unsigned y0 = cvtpk(s[ofs + 4], s[ofs + 5]);
      unsigned y1 = cvtpk(s[ofs + 6], s[ofs + 7]);
      permswap(x0, y0);   // x0 -> word0, y0 -> word2 (both lane halves)
      permswap(x1, y1);   // x1 -> word1, y1 -> word3
      u32x4 w; w[0] = x0; w[1] = x1; w[2] = y0; w[3] = y1;
      pf2[h] = __builtin_bit_cast(bf16x8, w);
    }

    // PV for this quarter's two k-slices (ks = 2kvq+h), VT rows lq / 32+lq
    __builtin_amdgcn_s_setprio(1);
#pragma unroll
    for (int c = 0; c < 2; ++c) {
      const int ks = 2 * kvq + c;
      const int cb = (32 * ks + 16 * hi) ^ swz;
      bf16x8 v0 = *(const bf16x8*)(vb + lq * 256        + cb);
      bf16x8 v1 = *(const bf16x8*)(vb + (32 + lq) * 256 + cb);
      o[0] = __builtin_amdgcn_mfma_f32_32x32x16_bf16(v0, pf2[c], o[0], 0, 0, 0);
      o[1] = __builtin_amdgcn_mfma_f32_32x32x16_bf16(v1, pf2[c], o[1], 0, 0, 0);
    }
    __builtin_amdgcn_s_setprio(0);
  };

  // prologue: stage tile 0 (both halves)
  issueH(0, 0); stageH(0, 0);
  issueH(0, 1); stageH(0, 1);
  __syncthreads();

  int pb = 0;
  for (int t = 0; t < NT; ++t) {
    const bool more = (t + 1 < NT);
    if (more) issueH(t + 1, 0);              // T14: issue early

    const char* kb = smem + pb * 16384;
    const char* vb = smem + 32768 + pb * 16384;

    quarter(kb, vb, 0);
    quarter(kb, vb, 1);
    if (more) { stageH(1 - pb, 0); issueH(t + 1, 1); }
    quarter(kb, vb, 2);
    quarter(kb, vb, 3);
    if (more) stageH(1 - pb, 1);

    __syncthreads();
    pb ^= 1;
  }

  // ---- epilogue: combine halves, O^T -> O via per-wave LDS transpose ----
  const float inv = 1.0f / (ps + __shfl_xor(ps, 32));
  float* ot = (float*)smem + wave * (32 * 33);
  const int q2 = lane >> 1, c2 = lane & 1;
#pragma unroll
  for (int db = 0; db < 2; ++db) {
    const f32x16& acc = o[db];
#pragma unroll
    for (int r = 0; r < 16; ++r)
      ot[lq * 33 + ((r & 3) + 8 * (r >> 2) + 4 * hi)] = acc[r] * inv;
    // per-wave buffer: same-wave LDS write->read ordered via lgkmcnt
    float* orow = Og + base + (size_t)(qw + q2) * Dd + 32 * db + 16 * c2;
#pragma unroll
    for (int j = 0; j < 4; ++j) {
      f32x4 w;
#pragma unroll
      for (int jj = 0; jj < 4; ++jj) w[jj] = ot[q2 * 33 + 16 * c2 + 4 * j + jj];
      *(f32x4*)(orow + 4 * j) = w;
    }
  }
}

extern "C" void kernel_launch(void* const* d_in, const int* in_sizes, int n_in,
                              void* d_out, int out_size, void* d_ws, size_t ws_size,
                              hipStream_t stream) {
  const float* q = (const float*)d_in[0];
  const float* k = (const float*)d_in[1];
  const float* v = (const float*)d_in[2];
  float* o = (float*)d_out;
  dim3 grid(8, 64);   // x: XCD group, y: (bh-sub, qtile)
  sdpa_fwd<<<grid, dim3(512), 0, stream>>>(q, k, v, o);
}

// Round 14
// 92.029 us; speedup vs baseline: 2.3338x; 2.3338x over previous
//
#include <hip/hip_runtime.h>
#include <hip/hip_bf16.h>

// B=4 H=16 S=2048 D=64, f32 in/out.
// Round 14: r9 exact (proven 92.3us) minus s_setprio (A/B: m190 showed
// setprio hurts barrier-lockstep structures; r9 is barrier-synced per tile).
// 8-wave blocks, QBLK=32/wave, role-split staging, swapped-QK^T 32x32x16,
// max-free exp2 softmax, permswap P-pack.

constexpr int Bb = 4, Hh = 16, Ss = 2048, Dd = 64;
constexpr float SCALE_LOG2E = 0.125f * 1.4426950408889634f; // D^-0.5 * log2(e)
constexpr int KVB = 64;
constexpr int NT = Ss / KVB;

typedef __bf16 bf16x8 __attribute__((ext_vector_type(8)));
typedef float  f32x4  __attribute__((ext_vector_type(4)));
typedef float  f32x16 __attribute__((ext_vector_type(16)));
typedef unsigned int u32x4 __attribute__((ext_vector_type(4)));

__device__ __forceinline__ unsigned cvtpk(float lo, float hi) {
  unsigned r;
  asm("v_cvt_pk_bf16_f32 %0, %1, %2" : "=v"(r) : "v"(lo), "v"(hi));
  return r;  // lo -> D[15:0], hi -> D[31:16]
}
// a.r1 <-> b.r0 (rows = 32-lane halves). After: a=[a.r0,b.r0], b=[a.r1,b.r1].
__device__ __forceinline__ void permswap(unsigned &a, unsigned &b) {
  asm("v_permlane32_swap_b32 %0, %1" : "+v"(a), "+v"(b));
}

__global__ __launch_bounds__(512, 4)
void sdpa_fwd(const float* __restrict__ Qg, const float* __restrict__ Kg,
              const float* __restrict__ Vg, float* __restrict__ Og) {
  // staging: K[2] 2x8KB + VT[2] 2x8KB (bf16 64x64, 128B rows, byte ^= (row&7)<<4)
  // epilogue overlay: 8 waves x [32][33] f32 = 33792B
  __shared__ __align__(16) char smem[33792];

  const int tid = threadIdx.x;
  const int wave = tid >> 6, lane = tid & 63;
  const int lq = lane & 31, hi = lane >> 5;
  const int swz = (lq & 7) << 4;

  const int bh = blockIdx.x * 8 + (blockIdx.y >> 3);
  const int qt = blockIdx.y & 7;
  const size_t base = (size_t)bh * (Ss * Dd);
  const int qw = qt * 256 + wave * 32;        // wave owns q rows [qw, qw+32)

  const float* Qp = Qg + base;
  const float* Kp = Kg + base;
  const float* Vp = Vg + base;

  // staging role split: waves 0-3 stage K, waves 4-7 stage V (256 threads each)
  const bool isK = (wave < 4);
  const int st  = tid & 255;
  const int skv = st >> 2, s4 = st & 3;       // K: row skv, 16 cols at 16*s4
  const int r2  = st >> 3, s8 = st & 7;       // V: rows 2r2,2r2+1, cols s8+8j

  // loop-invariant LDS read offsets (col-select ^ swizzle), bits 4-6
  int roff[4];
#pragma unroll
  for (int ds = 0; ds < 4; ++ds) roff[ds] = (32 * ds + 16 * hi) ^ swz;

  // ---- Q fragments: B-operand, col=q=lq, k=d=16*ds+8*hi+j ----
  bf16x8 qf[4];
  {
    const float* qp = Qp + (size_t)(qw + lq) * Dd;
#pragma unroll
    for (int ds = 0; ds < 4; ++ds) {
      f32x4 x0 = *(const f32x4*)(qp + 16 * ds + 8 * hi);
      f32x4 x1 = *(const f32x4*)(qp + 16 * ds + 8 * hi + 4);
#pragma unroll
      for (int j = 0; j < 4; ++j) {
        qf[ds][j]     = (__bf16)(x0[j] * SCALE_LOG2E);
        qf[ds][j + 4] = (__bf16)(x1[j] * SCALE_LOG2E);
      }
    }
  }

  f32x16 o[2];   // o[db]: O^T accumulators (d rows 32*db.., q col = lq)
#pragma unroll
  for (int a = 0; a < 2; ++a)
#pragma unroll
    for (int i = 0; i < 16; ++i) o[a][i] = 0.f;
  float ps = 0.f;   // per-lane partial row sum (combine across hi at end)

  f32x4 stg[4];     // shared staging regs for both roles (16 floats)

  auto issue = [&](int t) {
    if (isK) {
      const float* kp = Kp + (size_t)(t * KVB + skv) * Dd + 16 * s4;
#pragma unroll
      for (int i = 0; i < 4; ++i) stg[i] = *(const f32x4*)(kp + 4 * i);
    } else {
      const float* vp = Vp + (size_t)(t * KVB + 2 * r2) * Dd + s8;
#pragma unroll
      for (int j = 0; j < 8; ++j) {
        stg[j >> 2][j & 3]       = vp[8 * j];        // row 2r2
        stg[2 + (j >> 2)][j & 3] = vp[Dd + 8 * j];   // row 2r2+1
      }
    }
  };
  auto stage = [&](int buf) {
    char* kb = smem + buf * 8192;
    char* vb = smem + 16384 + buf * 8192;
    if (isK) {
#pragma unroll
      for (int c = 0; c < 2; ++c) {          // 2 x b128, swizzled slot
        u32x4 u;
        u[0] = cvtpk(stg[2 * c][0], stg[2 * c][1]);
        u[1] = cvtpk(stg[2 * c][2], stg[2 * c][3]);
        u[2] = cvtpk(stg[2 * c + 1][0], stg[2 * c + 1][1]);
        u[3] = cvtpk(stg[2 * c + 1][2], stg[2 * c + 1][3]);
        *(u32x4*)(kb + skv * 128 + 16 * ((2 * s4 + c) ^ (skv & 7))) = u;
      }
    } else {
#pragma unroll
      for (int j = 0; j < 8; ++j) {          // VT: 8 x b32 (kv pair packed)
        int d = s8 + 8 * j;
        *(unsigned*)(vb + d * 128 + ((4 * r2) ^ ((d & 7) << 4))) =
            cvtpk(stg[j >> 2][j & 3], stg[2 + (j >> 2)][j & 3]);
      }
    }
  };

  issue(0);
  stage(0);
  __syncthreads();

  int pb = 0;
  for (int t = 0; t < NT; ++t) {
    const bool more = (t + 1 < NT);
    if (more) issue(t + 1);                  // T14: issue early, write late

    const char* kb = smem + pb * 8192;
    const char* vb = smem + 16384 + pb * 8192;

    // ---- per kv-half: QK^T -> softmax -> pack -> PV (pf dies each half) ----
#pragma unroll
    for (int kvb = 0; kvb < 2; ++kvb) {
      f32x16 s;
#pragma unroll
      for (int i = 0; i < 16; ++i) s[i] = 0.f;
#pragma unroll
      for (int ds = 0; ds < 4; ++ds) {
        bf16x8 k0 = *(const bf16x8*)(kb + (32 * kvb + lq) * 128 + roff[ds]);
        s = __builtin_amdgcn_mfma_f32_32x32x16_bf16(k0, qf[ds], s, 0, 0, 0);
      }

      // max-free softmax: p = exp2(s); row-sum partial
#pragma unroll
      for (int i = 0; i < 16; ++i) s[i] = __builtin_amdgcn_exp2f(s[i]);
      {
        float u0 = 0.f, u1 = 0.f, u2 = 0.f, u3 = 0.f;
#pragma unroll
        for (int i = 0; i < 16; i += 4) {
          u0 += s[i]; u1 += s[i + 1]; u2 += s[i + 2]; u3 += s[i + 3];
        }
        ps += (u0 + u1) + (u2 + u3);
      }
      // pack to B-frags via permlane32_swap (T12)
      bf16x8 pf2[2];
#pragma unroll
      for (int h = 0; h < 2; ++h) {
        const int ofs = 8 * h;
        unsigned x0 = cvtpk(s[ofs + 0], s[ofs + 1]);
        unsigned x1 = cvtpk(s[ofs + 2], s[ofs + 3]);
        unsigned y0 = cvtpk(s[ofs + 4], s[ofs + 5]);
        unsigned y1 = cvtpk(s[ofs + 6], s[ofs + 7]);
        permswap(x0, y0);   // x0 -> word0, y0 -> word2 (both lane halves)
        permswap(x1, y1);   // x1 -> word1, y1 -> word3
        u32x4 w; w[0] = x0; w[1] = x1; w[2] = y0; w[3] = y1;
        pf2[h] = __builtin_bit_cast(bf16x8, w);
      }

      // PV for this half's two k-slices
#pragma unroll
      for (int c = 0; c < 2; ++c) {
        const int ks = 2 * kvb + c;
        bf16x8 v0 = *(const bf16x8*)(vb + lq * 128        + roff[ks]);
        bf16x8 v1 = *(const bf16x8*)(vb + (32 + lq) * 128 + roff[ks]);
        o[0] = __builtin_amdgcn_mfma_f32_32x32x16_bf16(v0, pf2[c], o[0], 0, 0, 0);
        o[1] = __builtin_amdgcn_mfma_f32_32x32x16_bf16(v1, pf2[c], o[1], 0, 0, 0);
      }
    }

    if (more) stage(1 - pb);                 // write late; vmcnt long satisfied
    __syncthreads();
    pb ^= 1;
  }

  // ---- epilogue: combine halves, O^T -> O via per-wave LDS transpose ----
  const float inv = 1.0f / (ps + __shfl_xor(ps, 32));
  float* ot = (float*)smem + wave * (32 * 33);
  const int q2 = lane >> 1, c2 = lane & 1;
#pragma unroll
  for (int db = 0; db < 2; ++db) {
    const f32x16& acc = o[db];
#pragma unroll
    for (int r = 0; r < 16; ++r)
      ot[lq * 33 + ((r & 3) + 8 * (r >> 2) + 4 * hi)] = acc[r] * inv;
    // per-wave buffer: same-wave LDS write->read ordered via lgkmcnt
    float* orow = Og + base + (size_t)(qw + q2) * Dd + 32 * db + 16 * c2;
#pragma unroll
    for (int j = 0; j < 4; ++j) {
      f32x4 w;
#pragma unroll
      for (int jj = 0; jj < 4; ++jj) w[jj] = ot[q2 * 33 + 16 * c2 + 4 * j + jj];
      *(f32x4*)(orow + 4 * j) = w;
    }
  }
}

extern "C" void kernel_launch(void* const* d_in, const int* in_sizes, int n_in,
                              void* d_out, int out_size, void* d_ws, size_t ws_size,
                              hipStream_t stream) {
  const float* q = (const float*)d_in[0];
  const float* k = (const float*)d_in[1];
  const float* v = (const float*)d_in[2];
  float* o = (float*)d_out;
  dim3 grid(8, 64);   // x: XCD group, y: (bh-sub, qtile)
  sdpa_fwd<<<grid, dim3(512), 0, stream>>>(q, k, v, o);
}

// Round 15
// 91.393 us; speedup vs baseline: 2.3501x; 1.0070x over previous
//
#include <hip/hip_runtime.h>
#include <hip/hip_bf16.h>

// B=4 H=16 S=2048 D=64, f32 in/out.
// Round 15: r14 exact (92.0us) + anti-phase stagger: odd blocks sleep ~800cy
// at entry so the 2 co-resident blocks/CU run half-a-tile out of phase
// (MFMA of one overlaps softmax-VALU/LDS of the other).

constexpr int Bb = 4, Hh = 16, Ss = 2048, Dd = 64;
constexpr float SCALE_LOG2E = 0.125f * 1.4426950408889634f; // D^-0.5 * log2(e)
constexpr int KVB = 64;
constexpr int NT = Ss / KVB;

typedef __bf16 bf16x8 __attribute__((ext_vector_type(8)));
typedef float  f32x4  __attribute__((ext_vector_type(4)));
typedef float  f32x16 __attribute__((ext_vector_type(16)));
typedef unsigned int u32x4 __attribute__((ext_vector_type(4)));

__device__ __forceinline__ unsigned cvtpk(float lo, float hi) {
  unsigned r;
  asm("v_cvt_pk_bf16_f32 %0, %1, %2" : "=v"(r) : "v"(lo), "v"(hi));
  return r;  // lo -> D[15:0], hi -> D[31:16]
}
// a.r1 <-> b.r0 (rows = 32-lane halves). After: a=[a.r0,b.r0], b=[a.r1,b.r1].
__device__ __forceinline__ void permswap(unsigned &a, unsigned &b) {
  asm("v_permlane32_swap_b32 %0, %1" : "+v"(a), "+v"(b));
}

__global__ __launch_bounds__(512, 4)
void sdpa_fwd(const float* __restrict__ Qg, const float* __restrict__ Kg,
              const float* __restrict__ Vg, float* __restrict__ Og) {
  // staging: K[2] 2x8KB + VT[2] 2x8KB (bf16 64x64, 128B rows, byte ^= (row&7)<<4)
  // epilogue overlay: 8 waves x [32][33] f32 = 33792B
  __shared__ __align__(16) char smem[33792];

  // anti-phase: odd blocks start ~half a tile late (13*64 ~ 830cy)
  if (blockIdx.y & 1) __builtin_amdgcn_s_sleep(13);

  const int tid = threadIdx.x;
  const int wave = tid >> 6, lane = tid & 63;
  const int lq = lane & 31, hi = lane >> 5;
  const int swz = (lq & 7) << 4;

  const int bh = blockIdx.x * 8 + (blockIdx.y >> 3);
  const int qt = blockIdx.y & 7;
  const size_t base = (size_t)bh * (Ss * Dd);
  const int qw = qt * 256 + wave * 32;        // wave owns q rows [qw, qw+32)

  const float* Qp = Qg + base;
  const float* Kp = Kg + base;
  const float* Vp = Vg + base;

  // staging role split: waves 0-3 stage K, waves 4-7 stage V (256 threads each)
  const bool isK = (wave < 4);
  const int st  = tid & 255;
  const int skv = st >> 2, s4 = st & 3;       // K: row skv, 16 cols at 16*s4
  const int r2  = st >> 3, s8 = st & 7;       // V: rows 2r2,2r2+1, cols s8+8j

  // loop-invariant LDS read offsets (col-select ^ swizzle), bits 4-6
  int roff[4];
#pragma unroll
  for (int ds = 0; ds < 4; ++ds) roff[ds] = (32 * ds + 16 * hi) ^ swz;

  // ---- Q fragments: B-operand, col=q=lq, k=d=16*ds+8*hi+j ----
  bf16x8 qf[4];
  {
    const float* qp = Qp + (size_t)(qw + lq) * Dd;
#pragma unroll
    for (int ds = 0; ds < 4; ++ds) {
      f32x4 x0 = *(const f32x4*)(qp + 16 * ds + 8 * hi);
      f32x4 x1 = *(const f32x4*)(qp + 16 * ds + 8 * hi + 4);
#pragma unroll
      for (int j = 0; j < 4; ++j) {
        qf[ds][j]     = (__bf16)(x0[j] * SCALE_LOG2E);
        qf[ds][j + 4] = (__bf16)(x1[j] * SCALE_LOG2E);
      }
    }
  }

  f32x16 o[2];   // o[db]: O^T accumulators (d rows 32*db.., q col = lq)
#pragma unroll
  for (int a = 0; a < 2; ++a)
#pragma unroll
    for (int i = 0; i < 16; ++i) o[a][i] = 0.f;
  float ps = 0.f;   // per-lane partial row sum (combine across hi at end)

  f32x4 stg[4];     // shared staging regs for both roles (16 floats)

  auto issue = [&](int t) {
    if (isK) {
      const float* kp = Kp + (size_t)(t * KVB + skv) * Dd + 16 * s4;
#pragma unroll
      for (int i = 0; i < 4; ++i) stg[i] = *(const f32x4*)(kp + 4 * i);
    } else {
      const float* vp = Vp + (size_t)(t * KVB + 2 * r2) * Dd + s8;
#pragma unroll
      for (int j = 0; j < 8; ++j) {
        stg[j >> 2][j & 3]       = vp[8 * j];        // row 2r2
        stg[2 + (j >> 2)][j & 3] = vp[Dd + 8 * j];   // row 2r2+1
      }
    }
  };
  auto stage = [&](int buf) {
    char* kb = smem + buf * 8192;
    char* vb = smem + 16384 + buf * 8192;
    if (isK) {
#pragma unroll
      for (int c = 0; c < 2; ++c) {          // 2 x b128, swizzled slot
        u32x4 u;
        u[0] = cvtpk(stg[2 * c][0], stg[2 * c][1]);
        u[1] = cvtpk(stg[2 * c][2], stg[2 * c][3]);
        u[2] = cvtpk(stg[2 * c + 1][0], stg[2 * c + 1][1]);
        u[3] = cvtpk(stg[2 * c + 1][2], stg[2 * c + 1][3]);
        *(u32x4*)(kb + skv * 128 + 16 * ((2 * s4 + c) ^ (skv & 7))) = u;
      }
    } else {
#pragma unroll
      for (int j = 0; j < 8; ++j) {          // VT: 8 x b32 (kv pair packed)
        int d = s8 + 8 * j;
        *(unsigned*)(vb + d * 128 + ((4 * r2) ^ ((d & 7) << 4))) =
            cvtpk(stg[j >> 2][j & 3], stg[2 + (j >> 2)][j & 3]);
      }
    }
  };

  issue(0);
  stage(0);
  __syncthreads();

  int pb = 0;
  for (int t = 0; t < NT; ++t) {
    const bool more = (t + 1 < NT);
    if (more) issue(t + 1);                  // T14: issue early, write late

    const char* kb = smem + pb * 8192;
    const char* vb = smem + 16384 + pb * 8192;

    // ---- per kv-half: QK^T -> softmax -> pack -> PV (pf dies each half) ----
#pragma unroll
    for (int kvb = 0; kvb < 2; ++kvb) {
      f32x16 s;
#pragma unroll
      for (int i = 0; i < 16; ++i) s[i] = 0.f;
#pragma unroll
      for (int ds = 0; ds < 4; ++ds) {
        bf16x8 k0 = *(const bf16x8*)(kb + (32 * kvb + lq) * 128 + roff[ds]);
        s = __builtin_amdgcn_mfma_f32_32x32x16_bf16(k0, qf[ds], s, 0, 0, 0);
      }

      // max-free softmax: p = exp2(s); row-sum partial
#pragma unroll
      for (int i = 0; i < 16; ++i) s[i] = __builtin_amdgcn_exp2f(s[i]);
      {
        float u0 = 0.f, u1 = 0.f, u2 = 0.f, u3 = 0.f;
#pragma unroll
        for (int i = 0; i < 16; i += 4) {
          u0 += s[i]; u1 += s[i + 1]; u2 += s[i + 2]; u3 += s[i + 3];
        }
        ps += (u0 + u1) + (u2 + u3);
      }
      // pack to B-frags via permlane32_swap (T12)
      bf16x8 pf2[2];
#pragma unroll
      for (int h = 0; h < 2; ++h) {
        const int ofs = 8 * h;
        unsigned x0 = cvtpk(s[ofs + 0], s[ofs + 1]);
        unsigned x1 = cvtpk(s[ofs + 2], s[ofs + 3]);
        unsigned y0 = cvtpk(s[ofs + 4], s[ofs + 5]);
        unsigned y1 = cvtpk(s[ofs + 6], s[ofs + 7]);
        permswap(x0, y0);   // x0 -> word0, y0 -> word2 (both lane halves)
        permswap(x1, y1);   // x1 -> word1, y1 -> word3
        u32x4 w; w[0] = x0; w[1] = x1; w[2] = y0; w[3] = y1;
        pf2[h] = __builtin_bit_cast(bf16x8, w);
      }

      // PV for this half's two k-slices
#pragma unroll
      for (int c = 0; c < 2; ++c) {
        const int ks = 2 * kvb + c;
        bf16x8 v0 = *(const bf16x8*)(vb + lq * 128        + roff[ks]);
        bf16x8 v1 = *(const bf16x8*)(vb + (32 + lq) * 128 + roff[ks]);
        o[0] = __builtin_amdgcn_mfma_f32_32x32x16_bf16(v0, pf2[c], o[0], 0, 0, 0);
        o[1] = __builtin_amdgcn_mfma_f32_32x32x16_bf16(v1, pf2[c], o[1], 0, 0, 0);
      }
    }

    if (more) stage(1 - pb);                 // write late; vmcnt long satisfied
    __syncthreads();
    pb ^= 1;
  }

  // ---- epilogue: combine halves, O^T -> O via per-wave LDS transpose ----
  const float inv = 1.0f / (ps + __shfl_xor(ps, 32));
  float* ot = (float*)smem + wave * (32 * 33);
  const int q2 = lane >> 1, c2 = lane & 1;
#pragma unroll
  for (int db = 0; db < 2; ++db) {
    const f32x16& acc = o[db];
#pragma unroll
    for (int r = 0; r < 16; ++r)
      ot[lq * 33 + ((r & 3) + 8 * (r >> 2) + 4 * hi)] = acc[r] * inv;
    // per-wave buffer: same-wave LDS write->read ordered via lgkmcnt
    float* orow = Og + base + (size_t)(qw + q2) * Dd + 32 * db + 16 * c2;
#pragma unroll
    for (int j = 0; j < 4; ++j) {
      f32x4 w;
#pragma unroll
      for (int jj = 0; jj < 4; ++jj) w[jj] = ot[q2 * 33 + 16 * c2 + 4 * j + jj];
      *(f32x4*)(orow + 4 * j) = w;
    }
  }
}

extern "C" void kernel_launch(void* const* d_in, const int* in_sizes, int n_in,
                              void* d_out, int out_size, void* d_ws, size_t ws_size,
                              hipStream_t stream) {
  const float* q = (const float*)d_in[0];
  const float* k = (const float*)d_in[1];
  const float* v = (const float*)d_in[2];
  float* o = (float*)d_out;
  dim3 grid(8, 64);   // x: XCD group, y: (bh-sub, qtile)
  sdpa_fwd<<<grid, dim3(512), 0, stream>>>(q, k, v, o);
}